// Round 1
// baseline (791.802 us; speedup 1.0000x reference)
//
#include <hip/hip_runtime.h>
#include <stdint.h>

#define N_    64
#define CIN   128
#define CMID  256
#define H_    56
#define W_    56
#define OH    28
#define OW    28
#define NPIX  (OH*OW)          // 784
#define CNT_CH (N_*NPIX)       // 50176
#define XWORDS 4
#define YWORDS 8
#define EPS_  1e-5f

// ---- workspace layout (bytes) ----
// stats (floats): 0 sumAbsW1, 1 sumAbsW2, 2 sumAbsWs
//   16..271 bn1_sum, 272..527 bn1_sq, 528..783 bn2_sum, 784..1039 bn2_sq
//   1040..1295 bn2_scale, 1296..1551 bn2_off
#define STATS_BYTES 8192
#define OFF_PW1 8192                       // u32[2304*4]  = 36864 B
#define OFF_PW2 (OFF_PW1 + 36864)          // u32[2304*8]  = 73728 B
#define OFF_PWS (OFF_PW2 + 73728)          // u32[256*4]   = 4096 B
#define OFF_PX  (OFF_PWS + 4096)           // u32[64*56*56*4] = 3211264 B
#define OFF_PY  (OFF_PX + 3211264)         // u32[64*784*8]   = 1605632 B
#define OFF_Y1  (OFF_PY + 1605632)         // int16[64*256*784] = 25690112 B
// total ~30.6 MB

__global__ __launch_bounds__(256) void reduce_abs_k(const float* __restrict__ w, int n,
                                                    float* __restrict__ out) {
  float s = 0.f;
  for (int i = blockIdx.x * blockDim.x + threadIdx.x; i < n; i += gridDim.x * blockDim.x)
    s += fabsf(w[i]);
  __shared__ float red[256];
  int tid = threadIdx.x;
  red[tid] = s; __syncthreads();
  for (int st = 128; st > 0; st >>= 1) {
    if (tid < st) red[tid] += red[tid + st];
    __syncthreads();
  }
  if (tid == 0) atomicAdd(out, red[0]);
}

__global__ __launch_bounds__(256) void pack_x_k(const float* __restrict__ x,
                                                uint32_t* __restrict__ px) {
  int idx = blockIdx.x * 256 + threadIdx.x;       // n*H*W + hw, 200704 total
  if (idx >= N_ * H_ * W_) return;
  int n = idx / (H_ * W_);
  int hw = idx - n * (H_ * W_);
  const float* xp = x + (size_t)n * CIN * H_ * W_ + hw;
  uint32_t wds[XWORDS] = {0u, 0u, 0u, 0u};
  for (int c = 0; c < CIN; ++c)
    if (xp[(size_t)c * (H_ * W_)] >= 0.f) wds[c >> 5] |= (1u << (c & 31));
  ((uint4*)px)[idx] = make_uint4(wds[0], wds[1], wds[2], wds[3]);
}

__global__ __launch_bounds__(256) void pack_w1_k(const float* __restrict__ w,
                                                 uint32_t* __restrict__ pw) {
  int idx = blockIdx.x * 256 + threadIdx.x;       // o*9+tap, 2304 total
  if (idx >= CMID * 9) return;
  int tap = idx % 9, o = idx / 9;
  const float* wp = w + (size_t)o * CIN * 9 + tap;
  uint32_t wds[4] = {0u, 0u, 0u, 0u};
  for (int c = 0; c < CIN; ++c)
    if (wp[(size_t)c * 9] >= 0.f) wds[c >> 5] |= (1u << (c & 31));
  ((uint4*)pw)[idx] = make_uint4(wds[0], wds[1], wds[2], wds[3]);
}

__global__ __launch_bounds__(256) void pack_w2_k(const float* __restrict__ w,
                                                 uint32_t* __restrict__ pw) {
  int idx = blockIdx.x * 256 + threadIdx.x;       // o*9+tap, 2304 total
  if (idx >= CMID * 9) return;
  int tap = idx % 9, o = idx / 9;
  const float* wp = w + (size_t)o * CMID * 9 + tap;
  uint32_t wds[8] = {0u,0u,0u,0u,0u,0u,0u,0u};
  for (int c = 0; c < CMID; ++c)
    if (wp[(size_t)c * 9] >= 0.f) wds[c >> 5] |= (1u << (c & 31));
  uint4* dst = (uint4*)pw + (size_t)idx * 2;
  dst[0] = make_uint4(wds[0], wds[1], wds[2], wds[3]);
  dst[1] = make_uint4(wds[4], wds[5], wds[6], wds[7]);
}

__global__ __launch_bounds__(256) void pack_ws_k(const float* __restrict__ w,
                                                 uint32_t* __restrict__ pw) {
  int o = threadIdx.x;                            // 256 threads
  const float* wp = w + (size_t)o * CIN;
  uint32_t wds[4] = {0u, 0u, 0u, 0u};
  for (int c = 0; c < CIN; ++c)
    if (wp[c] >= 0.f) wds[c >> 5] |= (1u << (c & 31));
  ((uint4*)pw)[o] = make_uint4(wds[0], wds[1], wds[2], wds[3]);
}

__global__ __launch_bounds__(256) void conv1_k(const uint32_t* __restrict__ px,
                                               const uint32_t* __restrict__ pw1,
                                               int16_t* __restrict__ y1,
                                               float* __restrict__ bn1_sum,
                                               float* __restrict__ bn1_sq) {
  int o = blockIdx.x % CMID;
  int n = blockIdx.x / CMID;
  int tid = threadIdx.x;
  __shared__ uint4 sw[9];
  if (tid < 9) sw[tid] = ((const uint4*)pw1)[o * 9 + tid];
  __syncthreads();
  const uint4* pxn = (const uint4*)px + (size_t)n * H_ * W_;
  int16_t* yo = y1 + (size_t)(n * CMID + o) * NPIX;
  float fsum = 0.f, fsq = 0.f;
  for (int pix = tid; pix < NPIX; pix += 256) {
    int oh = pix / OW, ow = pix - (pix / OW) * OW;
    int dot = 0;
#pragma unroll
    for (int kh = 0; kh < 3; ++kh) {
      int ih = 2 * oh - 1 + kh;
      if ((unsigned)ih >= (unsigned)H_) continue;
#pragma unroll
      for (int kw = 0; kw < 3; ++kw) {
        int iw = 2 * ow - 1 + kw;
        if ((unsigned)iw >= (unsigned)W_) continue;
        uint4 a = pxn[ih * W_ + iw];
        uint4 b = sw[kh * 3 + kw];
        int p = __popc(a.x ^ b.x) + __popc(a.y ^ b.y) + __popc(a.z ^ b.z) + __popc(a.w ^ b.w);
        dot += CIN - 2 * p;
      }
    }
    yo[pix] = (int16_t)dot;
    float fd = (float)dot;
    fsum += fd; fsq += fd * fd;
  }
  __shared__ float r1[256], r2[256];
  r1[tid] = fsum; r2[tid] = fsq; __syncthreads();
  for (int st = 128; st > 0; st >>= 1) {
    if (tid < st) { r1[tid] += r1[tid + st]; r2[tid] += r2[tid + st]; }
    __syncthreads();
  }
  if (tid == 0) { atomicAdd(&bn1_sum[o], r1[0]); atomicAdd(&bn1_sq[o], r2[0]); }
}

__global__ __launch_bounds__(256) void pack_y_k(const int16_t* __restrict__ y1,
                                                const float* __restrict__ stats,
                                                const float* __restrict__ g1,
                                                const float* __restrict__ b1,
                                                uint32_t* __restrict__ py) {
  __shared__ float sA[CMID], sB[CMID];
  int tid = threadIdx.x;
  {
    float alpha1 = stats[0] * (1.f / (CMID * CIN * 9));
    int c = tid;                                  // exactly 256 threads
    float S  = stats[16 + c];
    float S2 = stats[272 + c];
    float mu  = alpha1 * (S * (1.f / CNT_CH));
    float ey2 = alpha1 * alpha1 * (S2 * (1.f / CNT_CH));
    float var = fmaxf(ey2 - mu * mu, 0.f);
    float rs = rsqrtf(var + EPS_);
    float g = g1[c];
    sA[c] = g * rs * alpha1;       // applied to raw integer dot
    sB[c] = b1[c] - g * rs * mu;
  }
  __syncthreads();
  int idx = blockIdx.x * 256 + tid;               // n*NPIX + pix, 50176 total
  int n = idx / NPIX, pix = idx - (idx / NPIX) * NPIX;
  const int16_t* yp = y1 + (size_t)n * CMID * NPIX + pix;
  uint32_t wds[YWORDS];
#pragma unroll
  for (int wI = 0; wI < YWORDS; ++wI) wds[wI] = 0u;
  for (int c = 0; c < CMID; ++c) {
    float t = sA[c] * (float)yp[(size_t)c * NPIX] + sB[c];
    if (t >= 0.f) wds[c >> 5] |= (1u << (c & 31));
  }
  uint4* dst = (uint4*)py + (size_t)idx * 2;
  dst[0] = make_uint4(wds[0], wds[1], wds[2], wds[3]);
  dst[1] = make_uint4(wds[4], wds[5], wds[6], wds[7]);
}

__global__ __launch_bounds__(256) void conv2_k(const uint32_t* __restrict__ py,
                                               const uint32_t* __restrict__ pw2,
                                               const uint32_t* __restrict__ px,
                                               const uint32_t* __restrict__ pws,
                                               const float* __restrict__ stats,
                                               float* __restrict__ y2,
                                               float* __restrict__ bn2_sum,
                                               float* __restrict__ bn2_sq) {
  int o = blockIdx.x % CMID;
  int n = blockIdx.x / CMID;
  int tid = threadIdx.x;
  __shared__ uint4 sw[18];
  __shared__ uint4 swsct;
  if (tid < 18) sw[tid] = ((const uint4*)pw2)[o * 18 + tid];
  if (tid == 18) swsct = ((const uint4*)pws)[o];
  __syncthreads();
  float alpha2 = stats[1] * (1.f / (CMID * CMID * 9));
  float alphas = stats[2] * (1.f / (CMID * CIN));
  const uint4* pyn = (const uint4*)py + (size_t)n * NPIX * 2;
  const uint4* pxn = (const uint4*)px + (size_t)n * H_ * W_;
  float* yo = y2 + (size_t)(n * CMID + o) * NPIX;
  float fsum = 0.f, fsq = 0.f;
  for (int pix = tid; pix < NPIX; pix += 256) {
    int oh = pix / OW, ow = pix - (pix / OW) * OW;
    int dot2 = 0;
#pragma unroll
    for (int kh = 0; kh < 3; ++kh) {
      int ih = oh - 1 + kh;
      if ((unsigned)ih >= (unsigned)OH) continue;
#pragma unroll
      for (int kw = 0; kw < 3; ++kw) {
        int iw = ow - 1 + kw;
        if ((unsigned)iw >= (unsigned)OW) continue;
        const uint4* ap = pyn + (size_t)(ih * OW + iw) * 2;
        uint4 a0 = ap[0], a1 = ap[1];
        uint4 b0 = sw[(kh * 3 + kw) * 2], b1 = sw[(kh * 3 + kw) * 2 + 1];
        int p = __popc(a0.x ^ b0.x) + __popc(a0.y ^ b0.y) + __popc(a0.z ^ b0.z) + __popc(a0.w ^ b0.w)
              + __popc(a1.x ^ b1.x) + __popc(a1.y ^ b1.y) + __popc(a1.z ^ b1.z) + __popc(a1.w ^ b1.w);
        dot2 += CMID - 2 * p;
      }
    }
    uint4 ax = pxn[(2 * oh) * W_ + 2 * ow];
    int ps = __popc(ax.x ^ swsct.x) + __popc(ax.y ^ swsct.y) +
             __popc(ax.z ^ swsct.z) + __popc(ax.w ^ swsct.w);
    int dots = CIN - 2 * ps;
    float val = alpha2 * (float)dot2 + alphas * (float)dots;
    yo[pix] = val;
    fsum += val; fsq += val * val;
  }
  __shared__ float r1[256], r2[256];
  r1[tid] = fsum; r2[tid] = fsq; __syncthreads();
  for (int st = 128; st > 0; st >>= 1) {
    if (tid < st) { r1[tid] += r1[tid + st]; r2[tid] += r2[tid + st]; }
    __syncthreads();
  }
  if (tid == 0) { atomicAdd(&bn2_sum[o], r1[0]); atomicAdd(&bn2_sq[o], r2[0]); }
}

__global__ void bn2_prep_k(float* __restrict__ stats,
                           const float* __restrict__ g2,
                           const float* __restrict__ b2) {
  int c = threadIdx.x;                            // 1 block x 256
  float S = stats[528 + c], S2 = stats[784 + c];
  float mu = S * (1.f / CNT_CH);
  float var = fmaxf(S2 * (1.f / CNT_CH) - mu * mu, 0.f);
  float rs = rsqrtf(var + EPS_);
  float g = g2[c];
  stats[1040 + c] = g * rs;
  stats[1296 + c] = b2[c] - g * rs * mu;
}

__global__ __launch_bounds__(256) void bn2_apply_k(float* __restrict__ out,
                                                   const float* __restrict__ stats) {
  int idx = blockIdx.x * 256 + threadIdx.x;       // 12,845,056 = 50176 blocks exact
  int c = (idx / NPIX) % CMID;
  float v = out[idx];
  out[idx] = v * stats[1040 + c] + stats[1296 + c];
}

extern "C" void kernel_launch(void* const* d_in, const int* in_sizes, int n_in,
                              void* d_out, int out_size, void* d_ws, size_t ws_size,
                              hipStream_t stream) {
  const float* x   = (const float*)d_in[0];
  const float* w1  = (const float*)d_in[1];
  const float* g1  = (const float*)d_in[2];
  const float* b1  = (const float*)d_in[3];
  const float* w2  = (const float*)d_in[4];
  const float* g2  = (const float*)d_in[5];
  const float* b2  = (const float*)d_in[6];
  const float* wsc = (const float*)d_in[7];
  float* out = (float*)d_out;

  char* ws = (char*)d_ws;
  float*    stats = (float*)ws;
  uint32_t* pw1 = (uint32_t*)(ws + OFF_PW1);
  uint32_t* pw2 = (uint32_t*)(ws + OFF_PW2);
  uint32_t* pws = (uint32_t*)(ws + OFF_PWS);
  uint32_t* px  = (uint32_t*)(ws + OFF_PX);
  uint32_t* py  = (uint32_t*)(ws + OFF_PY);
  int16_t*  y1  = (int16_t*)(ws + OFF_Y1);

  hipMemsetAsync(ws, 0, STATS_BYTES, stream);

  reduce_abs_k<<<256, 256, 0, stream>>>(w1,  CMID * CIN * 9,  &stats[0]);
  reduce_abs_k<<<256, 256, 0, stream>>>(w2,  CMID * CMID * 9, &stats[1]);
  reduce_abs_k<<<64,  256, 0, stream>>>(wsc, CMID * CIN,      &stats[2]);

  pack_x_k<<<784, 256, 0, stream>>>(x, px);
  pack_w1_k<<<9, 256, 0, stream>>>(w1, pw1);
  pack_w2_k<<<9, 256, 0, stream>>>(w2, pw2);
  pack_ws_k<<<1, 256, 0, stream>>>(wsc, pws);

  conv1_k<<<N_ * CMID, 256, 0, stream>>>(px, pw1, y1, &stats[16], &stats[272]);
  pack_y_k<<<196, 256, 0, stream>>>(y1, stats, g1, b1, py);
  conv2_k<<<N_ * CMID, 256, 0, stream>>>(py, pw2, px, pws, stats, out,
                                         &stats[528], &stats[784]);
  bn2_prep_k<<<1, 256, 0, stream>>>(stats, g2, b2);
  bn2_apply_k<<<50176, 256, 0, stream>>>(out, stats);
}

// Round 2
// 523.017 us; speedup vs baseline: 1.5139x; 1.5139x over previous
//
#include <hip/hip_runtime.h>
#include <stdint.h>

#define N_    64
#define CIN   128
#define CMID  256
#define H_    56
#define W_    56
#define OH    28
#define OW    28
#define NPIX  (OH*OW)          // 784
#define CNT_CH (N_*NPIX)       // 50176
#define PXW   58               // padded conv1 input dim
#define PYW   30               // padded conv2 input dim
#define EPS_  1e-5f

// ---- workspace layout (bytes) ----
// stats floats: 0 sumAbsW1, 1 sumAbsW2, 2 sumAbsWs
//   16..271 bn1_sum, 272..527 bn1_sq, 528..783 bn2_sum, 784..1039 bn2_sq
//   1040..1295 bn2_scale, 1296..1551 bn2_off
#define STATS_BYTES 8192
#define OFF_PX  8192                        // u32[64*58*58*4]  = 3,444,736 B (zero-padded)
#define OFF_PY  (OFF_PX + 3444736)          // u32[64*30*30*8]  = 1,843,200 B (zero-padded)
#define OFF_PW1 (OFF_PY + 1843200)          // u32[256*9*4]   = 36,864 B
#define OFF_PW2 (OFF_PW1 + 36864)           // u32[256*9*8]   = 73,728 B
#define OFF_PWS (OFF_PW2 + 73728)           // u32[256*4]     = 4,096 B
#define OFF_Y1  (OFF_PWS + 4096)            // int16[64*256*784] = 25,690,112 B
#define MEMSET_BYTES OFF_PW1                // stats + px + py must start at 0

__device__ __forceinline__ uint32_t rfl(uint32_t v) {
  return (uint32_t)__builtin_amdgcn_readfirstlane((int)v);
}

__global__ __launch_bounds__(256) void reduce_abs_k(const float* __restrict__ w, int n,
                                                    float* __restrict__ out) {
  float s = 0.f;
  for (int i = blockIdx.x * 256 + threadIdx.x; i < n; i += gridDim.x * 256)
    s += fabsf(w[i]);
  for (int off = 32; off; off >>= 1) s += __shfl_down(s, off);
  if ((threadIdx.x & 63) == 0) atomicAdd(out, s);
}

// pack x -> padded [n][58*58][4 words], pad pre-zeroed by memset
__global__ __launch_bounds__(256) void pack_x_k(const float* __restrict__ x,
                                                uint32_t* __restrict__ px) {
  int idx = blockIdx.x * 256 + threadIdx.x;       // 200704 = 64*3136
  int n = idx / (H_ * W_);
  int hw = idx - n * (H_ * W_);
  int ih = hw / W_, iw = hw - (hw / W_) * W_;
  const float* xp = x + (size_t)n * CIN * H_ * W_ + hw;
  uint32_t wds[4] = {0u, 0u, 0u, 0u};
  for (int c = 0; c < CIN; ++c)
    if (xp[(size_t)c * (H_ * W_)] >= 0.f) wds[c >> 5] |= (1u << (c & 31));
  ((uint4*)px)[(size_t)n * (PXW * PXW) + (ih + 1) * PXW + (iw + 1)] =
      make_uint4(wds[0], wds[1], wds[2], wds[3]);
}

// pw1 layout [o][tap][4 words]
__global__ __launch_bounds__(256) void pack_w1_k(const float* __restrict__ w,
                                                 uint32_t* __restrict__ pw) {
  int idx = blockIdx.x * 256 + threadIdx.x;       // 9216 = 256*9*4
  int o = idx / 36, r = idx - (idx / 36) * 36;
  int t = r >> 2, word = r & 3;
  uint32_t bits = 0u;
  const float* wp = w + (size_t)o * CIN * 9 + t;
#pragma unroll
  for (int i = 0; i < 32; ++i)
    if (wp[(size_t)(word * 32 + i) * 9] >= 0.f) bits |= (1u << i);
  pw[o * 36 + t * 4 + word] = bits;
}

// pw2 layout [o][tap][8 words]
__global__ __launch_bounds__(256) void pack_w2_k(const float* __restrict__ w,
                                                 uint32_t* __restrict__ pw) {
  int idx = blockIdx.x * 256 + threadIdx.x;       // 18432 = 256*9*8
  int o = idx / 72, r = idx - (idx / 72) * 72;
  int t = r >> 3, word = r & 7;
  uint32_t bits = 0u;
  const float* wp = w + (size_t)o * CMID * 9 + t;
#pragma unroll
  for (int i = 0; i < 32; ++i)
    if (wp[(size_t)(word * 32 + i) * 9] >= 0.f) bits |= (1u << i);
  pw[o * 72 + t * 8 + word] = bits;
}

// pws layout [o][4 words]
__global__ __launch_bounds__(256) void pack_ws_k(const float* __restrict__ w,
                                                 uint32_t* __restrict__ pw) {
  int idx = blockIdx.x * 256 + threadIdx.x;       // 1024
  int o = idx >> 2, word = idx & 3;
  uint32_t bits = 0u;
  const float* wp = w + (size_t)o * CIN + word * 32;
#pragma unroll
  for (int i = 0; i < 32; ++i)
    if (wp[i] >= 0.f) bits |= (1u << i);
  pw[o * 4 + word] = bits;
}

// conv1: block = (n, o-pair). weights o0 in SGPRs, o1 in VGPRs. padded input,
// branch-free boundary compensation, wave-shuffle stats reduction.
__global__ __launch_bounds__(256) void conv1_k(const uint32_t* __restrict__ px,
                                               const uint32_t* __restrict__ pw1,
                                               int16_t* __restrict__ y1,
                                               float* __restrict__ bn1_sum,
                                               float* __restrict__ bn1_sq) {
  int og = blockIdx.x & 127;
  int n = blockIdx.x >> 7;
  int o0 = og * 2, o1 = o0 + 1;
  int tid = threadIdx.x;

  uint32_t s0[36], v1[36];
  {
    const uint4* q0 = (const uint4*)(pw1 + o0 * 36);
    const uint4* q1 = (const uint4*)(pw1 + o1 * 36);
#pragma unroll
    for (int j = 0; j < 9; ++j) {
      uint4 a = q0[j];
      s0[j * 4 + 0] = rfl(a.x); s0[j * 4 + 1] = rfl(a.y);
      s0[j * 4 + 2] = rfl(a.z); s0[j * 4 + 3] = rfl(a.w);
      uint4 b = q1[j];
      v1[j * 4 + 0] = b.x; v1[j * 4 + 1] = b.y; v1[j * 4 + 2] = b.z; v1[j * 4 + 3] = b.w;
    }
  }
  // pad-tap compensation constants: ct = 128 - 2*popc(weight_tap)
  int ct0[9], ct1[9];
#pragma unroll
  for (int t = 0; t < 9; ++t) {
    int p0 = __popc(s0[t * 4]) + __popc(s0[t * 4 + 1]) + __popc(s0[t * 4 + 2]) + __popc(s0[t * 4 + 3]);
    int p1 = __popc(v1[t * 4]) + __popc(v1[t * 4 + 1]) + __popc(v1[t * 4 + 2]) + __popc(v1[t * 4 + 3]);
    ct0[t] = CIN - 2 * p0; ct1[t] = CIN - 2 * p1;
  }
  int rh0 = ct0[0] + ct0[1] + ct0[2], rw0 = ct0[0] + ct0[3] + ct0[6];
  int rh1 = ct1[0] + ct1[1] + ct1[2], rw1 = ct1[0] + ct1[3] + ct1[6];

  const uint4* pxn = (const uint4*)px + (size_t)n * (PXW * PXW);
  int16_t* yo0 = y1 + (size_t)(n * CMID + o0) * NPIX;
  int16_t* yo1 = y1 + (size_t)(n * CMID + o1) * NPIX;
  float fs0 = 0.f, fq0 = 0.f, fs1 = 0.f, fq1 = 0.f;

  for (int pix = tid; pix < NPIX; pix += 256) {
    int oh = pix / OW, ow = pix - (pix / OW) * OW;
    int base = (2 * oh) * PXW + 2 * ow;       // tap (kh,kw) -> base + kh*PXW + kw
    int p0 = 0, p1 = 0;
#pragma unroll
    for (int kh = 0; kh < 3; ++kh) {
#pragma unroll
      for (int kw = 0; kw < 3; ++kw) {
        uint4 a = pxn[base + kh * PXW + kw];
        int t4 = (kh * 3 + kw) * 4;
        p0 += __popc(a.x ^ s0[t4]) + __popc(a.y ^ s0[t4 + 1]) +
              __popc(a.z ^ s0[t4 + 2]) + __popc(a.w ^ s0[t4 + 3]);
        p1 += __popc(a.x ^ v1[t4]) + __popc(a.y ^ v1[t4 + 1]) +
              __popc(a.z ^ v1[t4 + 2]) + __popc(a.w ^ v1[t4 + 3]);
      }
    }
    int corr0 = 0, corr1 = 0;
    if (oh == 0) { corr0 += rh0; corr1 += rh1; }
    if (ow == 0) { corr0 += rw0; corr1 += rw1; }
    if (oh == 0 && ow == 0) { corr0 -= ct0[0]; corr1 -= ct1[0]; }
    int d0 = 9 * CIN - 2 * p0 - corr0;
    int d1 = 9 * CIN - 2 * p1 - corr1;
    yo0[pix] = (int16_t)d0;
    yo1[pix] = (int16_t)d1;
    float f0 = (float)d0, f1 = (float)d1;
    fs0 += f0; fq0 += f0 * f0; fs1 += f1; fq1 += f1 * f1;
  }
  for (int off = 32; off; off >>= 1) {
    fs0 += __shfl_down(fs0, off); fq0 += __shfl_down(fq0, off);
    fs1 += __shfl_down(fs1, off); fq1 += __shfl_down(fq1, off);
  }
  if ((tid & 63) == 0) {
    atomicAdd(&bn1_sum[o0], fs0); atomicAdd(&bn1_sq[o0], fq0);
    atomicAdd(&bn1_sum[o1], fs1); atomicAdd(&bn1_sq[o1], fq1);
  }
}

// BN1 + sign + pack -> padded py [n][30*30][8 words]; thread = (pixel, quarter)
__global__ __launch_bounds__(256) void pack_y_k(const int16_t* __restrict__ y1,
                                                const float* __restrict__ stats,
                                                const float* __restrict__ g1,
                                                const float* __restrict__ b1,
                                                uint32_t* __restrict__ py) {
  __shared__ float2 sAB[CMID];
  int tid = threadIdx.x;
  {
    float alpha1 = stats[0] * (1.f / (CMID * CIN * 9));
    int c = tid;
    float S = stats[16 + c], S2 = stats[272 + c];
    float mu = alpha1 * (S * (1.f / CNT_CH));
    float ey2 = alpha1 * alpha1 * (S2 * (1.f / CNT_CH));
    float var = fmaxf(ey2 - mu * mu, 0.f);
    float rs = rsqrtf(var + EPS_);
    float g = g1[c];
    sAB[c] = make_float2(g * rs * alpha1, b1[c] - g * rs * mu);
  }
  __syncthreads();
  int idx = blockIdx.x * 256 + tid;               // 200704 = 50176*4
  int pg = idx >> 2, q = idx & 3;
  int n = pg / NPIX, pix = pg - n * NPIX;
  int oh = pix / OW, ow = pix - (pix / OW) * OW;
  const int16_t* yp = y1 + (size_t)n * CMID * NPIX + pix;
  int cb = q * 64;
  uint32_t w0 = 0u, w1 = 0u;
#pragma unroll
  for (int i = 0; i < 32; ++i) {
    float2 ab = sAB[cb + i];
    if (fmaf(ab.x, (float)yp[(size_t)(cb + i) * NPIX], ab.y) >= 0.f) w0 |= (1u << i);
  }
#pragma unroll
  for (int i = 0; i < 32; ++i) {
    float2 ab = sAB[cb + 32 + i];
    if (fmaf(ab.x, (float)yp[(size_t)(cb + 32 + i) * NPIX], ab.y) >= 0.f) w1 |= (1u << i);
  }
  size_t off = ((size_t)n * (PYW * PYW) + (oh + 1) * PYW + (ow + 1)) * 8 + q * 2;
  *(uint2*)(py + off) = make_uint2(w0, w1);
}

// conv2 + shortcut: block = (n, o-pair), same structure as conv1
__global__ __launch_bounds__(256) void conv2_k(const uint32_t* __restrict__ py,
                                               const uint32_t* __restrict__ pw2,
                                               const uint32_t* __restrict__ px,
                                               const uint32_t* __restrict__ pws,
                                               const float* __restrict__ stats,
                                               float* __restrict__ y2,
                                               float* __restrict__ bn2_sum,
                                               float* __restrict__ bn2_sq) {
  int og = blockIdx.x & 127;
  int n = blockIdx.x >> 7;
  int o0 = og * 2, o1 = o0 + 1;
  int tid = threadIdx.x;

  uint32_t s0[72], v1[72];
  {
    const uint4* q0 = (const uint4*)(pw2 + o0 * 72);
    const uint4* q1 = (const uint4*)(pw2 + o1 * 72);
#pragma unroll
    for (int j = 0; j < 18; ++j) {
      uint4 a = q0[j];
      s0[j * 4 + 0] = rfl(a.x); s0[j * 4 + 1] = rfl(a.y);
      s0[j * 4 + 2] = rfl(a.z); s0[j * 4 + 3] = rfl(a.w);
      uint4 b = q1[j];
      v1[j * 4 + 0] = b.x; v1[j * 4 + 1] = b.y; v1[j * 4 + 2] = b.z; v1[j * 4 + 3] = b.w;
    }
  }
  uint32_t sc0[4], sc1[4];
  {
    uint4 a = ((const uint4*)pws)[o0];
    sc0[0] = rfl(a.x); sc0[1] = rfl(a.y); sc0[2] = rfl(a.z); sc0[3] = rfl(a.w);
    uint4 b = ((const uint4*)pws)[o1];
    sc1[0] = b.x; sc1[1] = b.y; sc1[2] = b.z; sc1[3] = b.w;
  }
  int ct0[9], ct1[9];
#pragma unroll
  for (int t = 0; t < 9; ++t) {
    int p0 = 0, p1 = 0;
#pragma unroll
    for (int j = 0; j < 8; ++j) { p0 += __popc(s0[t * 8 + j]); p1 += __popc(v1[t * 8 + j]); }
    ct0[t] = CMID - 2 * p0; ct1[t] = CMID - 2 * p1;
  }
  int rhT0 = ct0[0] + ct0[1] + ct0[2], rhB0 = ct0[6] + ct0[7] + ct0[8];
  int rwL0 = ct0[0] + ct0[3] + ct0[6], rwR0 = ct0[2] + ct0[5] + ct0[8];
  int rhT1 = ct1[0] + ct1[1] + ct1[2], rhB1 = ct1[6] + ct1[7] + ct1[8];
  int rwL1 = ct1[0] + ct1[3] + ct1[6], rwR1 = ct1[2] + ct1[5] + ct1[8];

  float alpha2 = stats[1] * (1.f / (CMID * CMID * 9));
  float alphas = stats[2] * (1.f / (CMID * CIN));
  const uint4* pyn = (const uint4*)py + (size_t)n * (PYW * PYW) * 2;
  const uint4* pxn = (const uint4*)px + (size_t)n * (PXW * PXW);
  float* yo0 = y2 + (size_t)(n * CMID + o0) * NPIX;
  float* yo1 = y2 + (size_t)(n * CMID + o1) * NPIX;
  float fs0 = 0.f, fq0 = 0.f, fs1 = 0.f, fq1 = 0.f;

  for (int pix = tid; pix < NPIX; pix += 256) {
    int oh = pix / OW, ow = pix - (pix / OW) * OW;
    int base = (oh * PYW + ow) * 2;            // tap (kh,kw): base + (kh*PYW+kw)*2
    int p0 = 0, p1 = 0;
#pragma unroll
    for (int kh = 0; kh < 3; ++kh) {
#pragma unroll
      for (int kw = 0; kw < 3; ++kw) {
        const uint4* ap = pyn + base + (kh * PYW + kw) * 2;
        uint4 a0 = ap[0], a1 = ap[1];
        int t8 = (kh * 3 + kw) * 8;
        p0 += __popc(a0.x ^ s0[t8]) + __popc(a0.y ^ s0[t8 + 1]) +
              __popc(a0.z ^ s0[t8 + 2]) + __popc(a0.w ^ s0[t8 + 3]) +
              __popc(a1.x ^ s0[t8 + 4]) + __popc(a1.y ^ s0[t8 + 5]) +
              __popc(a1.z ^ s0[t8 + 6]) + __popc(a1.w ^ s0[t8 + 7]);
        p1 += __popc(a0.x ^ v1[t8]) + __popc(a0.y ^ v1[t8 + 1]) +
              __popc(a0.z ^ v1[t8 + 2]) + __popc(a0.w ^ v1[t8 + 3]) +
              __popc(a1.x ^ v1[t8 + 4]) + __popc(a1.y ^ v1[t8 + 5]) +
              __popc(a1.z ^ v1[t8 + 6]) + __popc(a1.w ^ v1[t8 + 7]);
      }
    }
    int corr0 = 0, corr1 = 0;
    if (oh == 0)  { corr0 += rhT0; corr1 += rhT1; }
    if (oh == 27) { corr0 += rhB0; corr1 += rhB1; }
    if (ow == 0)  { corr0 += rwL0; corr1 += rwL1; }
    if (ow == 27) { corr0 += rwR0; corr1 += rwR1; }
    if (oh == 0 && ow == 0)   { corr0 -= ct0[0]; corr1 -= ct1[0]; }
    if (oh == 0 && ow == 27)  { corr0 -= ct0[2]; corr1 -= ct1[2]; }
    if (oh == 27 && ow == 0)  { corr0 -= ct0[6]; corr1 -= ct1[6]; }
    if (oh == 27 && ow == 27) { corr0 -= ct0[8]; corr1 -= ct1[8]; }
    int d0 = 9 * CMID - 2 * p0 - corr0;
    int d1 = 9 * CMID - 2 * p1 - corr1;
    // 1x1 stride-2 shortcut (always valid, no padding)
    uint4 ax = pxn[(2 * oh + 1) * PXW + (2 * ow + 1)];
    int ps0 = __popc(ax.x ^ sc0[0]) + __popc(ax.y ^ sc0[1]) +
              __popc(ax.z ^ sc0[2]) + __popc(ax.w ^ sc0[3]);
    int ps1 = __popc(ax.x ^ sc1[0]) + __popc(ax.y ^ sc1[1]) +
              __popc(ax.z ^ sc1[2]) + __popc(ax.w ^ sc1[3]);
    float v0 = alpha2 * (float)d0 + alphas * (float)(CIN - 2 * ps0);
    float vv1 = alpha2 * (float)d1 + alphas * (float)(CIN - 2 * ps1);
    yo0[pix] = v0; yo1[pix] = vv1;
    fs0 += v0; fq0 += v0 * v0; fs1 += vv1; fq1 += vv1 * vv1;
  }
  for (int off = 32; off; off >>= 1) {
    fs0 += __shfl_down(fs0, off); fq0 += __shfl_down(fq0, off);
    fs1 += __shfl_down(fs1, off); fq1 += __shfl_down(fq1, off);
  }
  if ((tid & 63) == 0) {
    atomicAdd(&bn2_sum[o0], fs0); atomicAdd(&bn2_sq[o0], fq0);
    atomicAdd(&bn2_sum[o1], fs1); atomicAdd(&bn2_sq[o1], fq1);
  }
}

__global__ void bn2_prep_k(float* __restrict__ stats,
                           const float* __restrict__ g2,
                           const float* __restrict__ b2) {
  int c = threadIdx.x;                            // 1 block x 256
  float S = stats[528 + c], S2 = stats[784 + c];
  float mu = S * (1.f / CNT_CH);
  float var = fmaxf(S2 * (1.f / CNT_CH) - mu * mu, 0.f);
  float rs = rsqrtf(var + EPS_);
  float g = g2[c];
  stats[1040 + c] = g * rs;
  stats[1296 + c] = b2[c] - g * rs * mu;
}

__global__ __launch_bounds__(256) void bn2_apply_k(float4* __restrict__ out,
                                                   const float* __restrict__ stats) {
  int idx = blockIdx.x * 256 + threadIdx.x;       // 3,211,264 float4s = 12544 blocks
  int c = (idx / (NPIX / 4)) & (CMID - 1);
  float sc = stats[1040 + c], of = stats[1296 + c];
  float4 v = out[idx];
  v.x = v.x * sc + of; v.y = v.y * sc + of; v.z = v.z * sc + of; v.w = v.w * sc + of;
  out[idx] = v;
}

extern "C" void kernel_launch(void* const* d_in, const int* in_sizes, int n_in,
                              void* d_out, int out_size, void* d_ws, size_t ws_size,
                              hipStream_t stream) {
  const float* x   = (const float*)d_in[0];
  const float* w1  = (const float*)d_in[1];
  const float* g1  = (const float*)d_in[2];
  const float* b1  = (const float*)d_in[3];
  const float* w2  = (const float*)d_in[4];
  const float* g2  = (const float*)d_in[5];
  const float* b2  = (const float*)d_in[6];
  const float* wsc = (const float*)d_in[7];
  float* out = (float*)d_out;

  char* ws = (char*)d_ws;
  float*    stats = (float*)ws;
  uint32_t* px  = (uint32_t*)(ws + OFF_PX);
  uint32_t* py  = (uint32_t*)(ws + OFF_PY);
  uint32_t* pw1 = (uint32_t*)(ws + OFF_PW1);
  uint32_t* pw2 = (uint32_t*)(ws + OFF_PW2);
  uint32_t* pws = (uint32_t*)(ws + OFF_PWS);
  int16_t*  y1  = (int16_t*)(ws + OFF_Y1);

  // zero stats + padded px + padded py in one shot
  hipMemsetAsync(ws, 0, MEMSET_BYTES, stream);

  reduce_abs_k<<<128, 256, 0, stream>>>(w1,  CMID * CIN * 9,  &stats[0]);
  reduce_abs_k<<<256, 256, 0, stream>>>(w2,  CMID * CMID * 9, &stats[1]);
  reduce_abs_k<<<32,  256, 0, stream>>>(wsc, CMID * CIN,      &stats[2]);

  pack_x_k<<<784, 256, 0, stream>>>(x, px);
  pack_w1_k<<<36, 256, 0, stream>>>(w1, pw1);
  pack_w2_k<<<72, 256, 0, stream>>>(w2, pw2);
  pack_ws_k<<<4, 256, 0, stream>>>(wsc, pws);

  conv1_k<<<N_ * 128, 256, 0, stream>>>(px, pw1, y1, &stats[16], &stats[272]);
  pack_y_k<<<784, 256, 0, stream>>>(y1, stats, g1, b1, py);
  conv2_k<<<N_ * 128, 256, 0, stream>>>(py, pw2, px, pws, stats, out,
                                        &stats[528], &stats[784]);
  bn2_prep_k<<<1, 256, 0, stream>>>(stats, g2, b2);
  bn2_apply_k<<<12544, 256, 0, stream>>>((float4*)out, stats);
}